// Round 14
// baseline (445.905 us; speedup 1.0000x reference)
//
#include <hip/hip_runtime.h>
#include <hip/hip_bf16.h>
#include <hip/hip_fp16.h>

#define E4M3_MAX 240.0f

typedef __attribute__((ext_vector_type(8))) __bf16 bf16x8;
typedef __attribute__((ext_vector_type(4))) float f32x4;
typedef unsigned short ushort_t;

__device__ __forceinline__ void gload_lds16(const void* g, void* l) {
  __builtin_amdgcn_global_load_lds(
      (const __attribute__((address_space(1))) void*)g,
      (__attribute__((address_space(3))) void*)l,
      16, 0, 0);
}

// ---------------- amax over |weight| ----------------
__global__ void amax_abs_kernel(const float* __restrict__ w, int n4,
                                unsigned* __restrict__ amax_bits) {
  float m = 0.0f;
  const float4* w4 = (const float4*)w;
  int stride = gridDim.x * blockDim.x;
  for (int i = blockIdx.x * blockDim.x + threadIdx.x; i < n4; i += stride) {
    float4 v = w4[i];
    m = fmaxf(m, fmaxf(fmaxf(fabsf(v.x), fabsf(v.y)),
                       fmaxf(fabsf(v.z), fabsf(v.w))));
  }
  for (int off = 32; off > 0; off >>= 1)
    m = fmaxf(m, __shfl_down(m, off, 64));
  __shared__ float smax[4];
  int l = threadIdx.x & 63, wv = threadIdx.x >> 6;
  if (l == 0) smax[wv] = m;
  __syncthreads();
  if (threadIdx.x == 0) {
    float bm = fmaxf(fmaxf(smax[0], smax[1]), fmaxf(smax[2], smax[3]));
    atomicMax(amax_bits, __float_as_uint(bm));
  }
}

// ---------------- quantize weight -> bf16 qw ----------------
__global__ void quant_weight_kernel(const float* __restrict__ w,
                                    const unsigned* __restrict__ amax_bits,
                                    ushort_t* __restrict__ qw, int n4) {
  float amax = __uint_as_float(*amax_bits);
  float scale = fmaxf(amax / E4M3_MAX, 1e-10f);
  const float4* w4 = (const float4*)w;
  ushort4* q4 = (ushort4*)qw;
  int stride = gridDim.x * blockDim.x;
  for (int i = blockIdx.x * blockDim.x + threadIdx.x; i < n4; i += stride) {
    float4 v = w4[i];
    float r[4] = {v.x, v.y, v.z, v.w};
    ushort_t o[4];
#pragma unroll
    for (int j = 0; j < 4; ++j) {
      float s = fminf(fmaxf(r[j] / scale, -E4M3_MAX), E4M3_MAX);
      s = __half2float(__float2half(s));   // fp16 round-trip (RNE)
      float q = rintf(s * 8.0f) * 0.125f;  // mantissa grid, half-to-even
      q = fminf(fmaxf(q, -E4M3_MAX), E4M3_MAX);
      __hip_bfloat16 h = __float2bfloat16(q * scale);
      o[j] = *(ushort_t*)&h;
    }
    ushort4 ov = {o[0], o[1], o[2], o[3]};
    q4[i] = ov;
  }
}

// ---------------- convert x fp32 -> bf16 ----------------
__global__ void cvt_bf16_kernel(const float* __restrict__ x,
                                ushort_t* __restrict__ xb, int n4) {
  const float4* x4 = (const float4*)x;
  ushort4* o4 = (ushort4*)xb;
  int stride = gridDim.x * blockDim.x;
  for (int i = blockIdx.x * blockDim.x + threadIdx.x; i < n4; i += stride) {
    float4 v = x4[i];
    __hip_bfloat16 h0 = __float2bfloat16(v.x);
    __hip_bfloat16 h1 = __float2bfloat16(v.y);
    __hip_bfloat16 h2 = __float2bfloat16(v.z);
    __hip_bfloat16 h3 = __float2bfloat16(v.w);
    ushort4 o = {*(ushort_t*)&h0, *(ushort_t*)&h1,
                 *(ushort_t*)&h2, *(ushort_t*)&h3};
    o4[i] = o;
  }
}

// == 256x256 bf16 GEMM — small-batch quadrant pipeline (4/8/8/4 reads/phase) ==
// C = A * Bt^T + bias.  A: [8192][4096] bf16, Bt: [4096][4096] bf16, C fp32.
// 8 waves (2M x 4N), 16x16x32 MFMA, BK=64, dbuf LDS 128 KiB.
// Per K-tile t (buf b), 4 phases of 16 MFMA (one C-quadrant x K=64) each:
//  t.1: rd bfQ(t)[4]          |                      | MMA H0J0 (afE,bfP)
//  t.2: rd afO(t)[8]          |                      | MMA H0J1 (afE,bfQ); VMC0
//  t.3: rd afE(t+1)[8]        | stage Bh0(t+2)->b    | MMA H1J1 (afO,bfQ)
//  t.4: rd bfP'(t+1)[4]       | stage Bh1+Ah0+Ah1    | MMA H1J0 (afO,bfP)
// Every lgkmcnt(0) covers a batch issued BEFORE the preceding barrier (4-8
// reads) -> near-free.  VMC0@t.2 drains t+1's stages (youngest >=2 phases
// old); t.3/t.4 then read t+1 safely.  bfP is parity-double-buffered
// (bfPe/bfPo); afE/afO/bfQ overwritten only after last use (ledger-checked).

#define BAR() do { asm volatile("" ::: "memory"); \
                   __builtin_amdgcn_s_barrier(); \
                   asm volatile("" ::: "memory"); } while (0)
#define LGKM0() asm volatile("s_waitcnt lgkmcnt(0)" ::: "memory")
#define VMC8() asm volatile("s_waitcnt vmcnt(8)" ::: "memory")
#define VMC0() asm volatile("s_waitcnt vmcnt(0)" ::: "memory")

__global__ __launch_bounds__(512, 2) void gemm256_sb(
    const ushort_t* __restrict__ A, const ushort_t* __restrict__ Bt,
    const float* __restrict__ bias, float* __restrict__ C) {
  constexpr int K = 4096, N = 4096;
  __shared__ __align__(16) ushort_t As[2][2][8192];
  __shared__ __align__(16) ushort_t Bs[2][2][8192];

  const int tid = threadIdx.x;
  const int wid = tid >> 6, lane = tid & 63;
  const int wm = wid >> 2, wn = wid & 3;     // 2 x 4 wave grid
  const int lk = lane >> 4, lr = lane & 15;

  // XCD swizzle (nwg = 512, divisible by 8)
  int bid = blockIdx.x;
  int swz = (bid & 7) * 64 + (bid >> 3);
  int bm = swz >> 4, bn = swz & 15;          // nbn = 16

  const ushort_t* Ab = A + (size_t)bm * 256 * K;
  const ushort_t* Bb = Bt + (size_t)bn * 256 * K;

  // staging: slot s = q*512+tid; row = s>>3; granule c = (s&7)^(row&7)
  int offG[2];
#pragma unroll
  for (int q = 0; q < 2; ++q) {
    int s = q * 512 + tid;
    int row = s >> 3;
    int c = (s & 7) ^ (row & 7);
    offG[q] = row * K + c * 8;
  }

#define STAGE_AH(buf, kt, h)                                               \
  do { _Pragma("unroll") for (int q = 0; q < 2; ++q)                       \
    gload_lds16(Ab + (size_t)(h) * 128 * K + (kt) * 64 + offG[q],          \
                &As[buf][h][(q * 512 + wid * 64) * 8]); } while (0)
#define STAGE_BH(buf, kt, h)                                               \
  do { _Pragma("unroll") for (int q = 0; q < 2; ++q)                       \
    gload_lds16(Bb + (size_t)(h) * 128 * K + (kt) * 64 + offG[q],          \
                &Bs[buf][h][(q * 512 + wid * 64) * 8]); } while (0)

  // swizzled ds_read addressing (R2-verified, 0 conflicts)
  const int abase = lr * 64;
  const int bbase = (wn & 1) * 4096 + lr * 64;
  const int bhalf = wn >> 1;
  const int xk0 = ((lk) ^ (lr & 7)) * 8;
  const int xk1 = ((4 + lk) ^ (lr & 7)) * 8;

  bf16x8 afE[4][2], afO[4][2], bfQ[2][2], bfPe[2][2], bfPo[2][2];
  f32x4 acc[8][4] = {};

#define RDA(AF, fi0, cb)                                                   \
  do { _Pragma("unroll") for (int i = 0; i < 4; ++i) {                     \
    AF[i][0] = *(const bf16x8*)&As[cb][wm][abase + ((fi0) + i) * 1024 + xk0]; \
    AF[i][1] = *(const bf16x8*)&As[cb][wm][abase + ((fi0) + i) * 1024 + xk1]; \
  } } while (0)
#define RDB(BF, fj0, cb)                                                   \
  do { _Pragma("unroll") for (int j = 0; j < 2; ++j) {                     \
    BF[j][0] = *(const bf16x8*)&Bs[cb][bhalf][bbase + ((fj0) + j) * 1024 + xk0]; \
    BF[j][1] = *(const bf16x8*)&Bs[cb][bhalf][bbase + ((fj0) + j) * 1024 + xk1]; \
  } } while (0)

  // one C-quadrant x K=64: 4 fi x 2 fj x 2 ks = 16 MFMA
#define MMAQ(AF, fi0, BF, fj0)                                             \
  do { __builtin_amdgcn_s_setprio(1);                                      \
    _Pragma("unroll") for (int i = 0; i < 4; ++i)                          \
      _Pragma("unroll") for (int j = 0; j < 2; ++j) {                      \
        acc[(fi0) + i][(fj0) + j] = __builtin_amdgcn_mfma_f32_16x16x32_bf16( \
            AF[i][0], BF[j][0], acc[(fi0) + i][(fj0) + j], 0, 0, 0);       \
        acc[(fi0) + i][(fj0) + j] = __builtin_amdgcn_mfma_f32_16x16x32_bf16( \
            AF[i][1], BF[j][1], acc[(fi0) + i][(fj0) + j], 0, 0, 0);       \
      }                                                                    \
    __builtin_amdgcn_s_setprio(0); } while (0)

  // BP = this tile's bfP set; BPn = set to fill with bfP(t+1).
#define TILE(b, t, BP, BPn, DO_S, DO_R)                                    \
  do {                                                                     \
    /* Ph1 */                                                              \
    RDB(bfQ, 2, b);                                                        \
    BAR(); LGKM0(); MMAQ(afE, 0, BP, 0); BAR();                            \
    /* Ph2 */                                                              \
    RDA(afO, 4, b);                                                        \
    BAR(); LGKM0(); MMAQ(afE, 0, bfQ, 2); VMC0(); BAR();                   \
    /* Ph3 */                                                              \
    if (DO_R) RDA(afE, 0, (b) ^ 1);                                        \
    if (DO_S) STAGE_BH(b, (t) + 2, 0);                                     \
    BAR(); LGKM0(); MMAQ(afO, 4, bfQ, 2); BAR();                           \
    /* Ph4 */                                                              \
    if (DO_R) RDB(BPn, 0, (b) ^ 1);                                        \
    if (DO_S) { STAGE_BH(b, (t) + 2, 1);                                   \
                STAGE_AH(b, (t) + 2, 0); STAGE_AH(b, (t) + 2, 1); }        \
    BAR(); LGKM0(); MMAQ(afO, 4, BP, 0); BAR();                            \
  } while (0)

  // ---- prologue: tiles 0 (buf0) and 1 (buf1) fully staged ----
  STAGE_BH(0, 0, 0); STAGE_BH(0, 0, 1);
  STAGE_AH(0, 0, 0); STAGE_AH(0, 0, 1);
  STAGE_BH(1, 1, 0); STAGE_BH(1, 1, 1);
  STAGE_AH(1, 1, 0); STAGE_AH(1, 1, 1);
  VMC8();   // tile 0 retired; tile 1's 8 loads in flight (drained @0.Ph2)
  BAR();
  RDA(afE, 0, 0); RDB(bfPe, 0, 0);   // tile 0 first-quadrant frags (12)

  // ---- main loop: tiles 0..61 ----
  for (int t = 0; t < 62; t += 2) {
    TILE(0, t,     bfPe, bfPo, 1, 1);
    TILE(1, t + 1, bfPo, bfPe, 1, 1);
  }
  // t=60/61 staged tiles 62,63; 62's VMC0@Ph2 drains 61.4's stages of 63.
  // ---- tail: tile 62 (reads 63's frags, no stages), tile 63 (bare) ----
  TILE(0, 62, bfPe, bfPo, 0, 1);
  TILE(1, 63, bfPo, bfPe, 0, 0);

  // ---- C write + bias (16x16 D: col = lane&15 -> n, row = lk*4 + reg -> m) ----
  float* Cb = C + (size_t)(bm * 256 + wm * 128) * N + bn * 256 + wn * 64;
#pragma unroll
  for (int fj = 0; fj < 4; ++fj) {
    int n = fj * 16 + lr;
    float bv = bias[bn * 256 + wn * 64 + n];
#pragma unroll
    for (int fi = 0; fi < 8; ++fi) {
      int m0 = fi * 16 + lk * 4;
#pragma unroll
      for (int r = 0; r < 4; ++r)
        Cb[(size_t)(m0 + r) * N + n] = acc[fi][fj][r] + bv;
    }
  }
}

extern "C" void kernel_launch(void* const* d_in, const int* in_sizes, int n_in,
                              void* d_out, int out_size, void* d_ws, size_t ws_size,
                              hipStream_t stream) {
  const float* x = (const float*)d_in[0];     // [4,2048,4096] fp32
  const float* wt = (const float*)d_in[1];    // [4096,4096] fp32
  const float* bias = (const float*)d_in[2];  // [4096] fp32
  float* out = (float*)d_out;                 // [4,2048,4096] fp32

  const int DIN = 4096;
  const int NW = in_sizes[1];                 // 16777216
  const int M = in_sizes[0] / DIN;            // 8192

  char* ws = (char*)d_ws;
  unsigned* amax_bits = (unsigned*)ws;
  ushort_t* qw = (ushort_t*)(ws + 256);                    // bf16 [4096][4096]
  ushort_t* xb = (ushort_t*)(ws + 256 + (size_t)NW * 2);   // bf16 [8192][4096]

  hipMemsetAsync(amax_bits, 0, 4, stream);
  hipLaunchKernelGGL(amax_abs_kernel, dim3(1024), dim3(256), 0, stream,
                     wt, NW / 4, amax_bits);
  hipLaunchKernelGGL(quant_weight_kernel, dim3(2048), dim3(256), 0, stream,
                     wt, amax_bits, qw, NW / 4);
  hipLaunchKernelGGL(cvt_bf16_kernel, dim3(2048), dim3(256), 0, stream,
                     x, xb, (M * DIN) / 4);

  hipLaunchKernelGGL(gemm256_sb, dim3(512), dim3(512), 0, stream,
                     xb, qw, bias, out);
}

// Round 15
// 325.607 us; speedup vs baseline: 1.3695x; 1.3695x over previous
//
#include <hip/hip_runtime.h>
#include <hip/hip_bf16.h>
#include <hip/hip_fp16.h>

#define E4M3_MAX 240.0f

typedef __attribute__((ext_vector_type(8))) __bf16 bf16x8;
typedef __attribute__((ext_vector_type(16))) float f32x16;
typedef unsigned short ushort_t;

__device__ __forceinline__ void gload_lds16(const void* g, void* l) {
  __builtin_amdgcn_global_load_lds(
      (const __attribute__((address_space(1))) void*)g,
      (__attribute__((address_space(3))) void*)l,
      16, 0, 0);
}

// ---------------- amax over |weight| ----------------
__global__ void amax_abs_kernel(const float* __restrict__ w, int n4,
                                unsigned* __restrict__ amax_bits) {
  float m = 0.0f;
  const float4* w4 = (const float4*)w;
  int stride = gridDim.x * blockDim.x;
  for (int i = blockIdx.x * blockDim.x + threadIdx.x; i < n4; i += stride) {
    float4 v = w4[i];
    m = fmaxf(m, fmaxf(fmaxf(fabsf(v.x), fabsf(v.y)),
                       fmaxf(fabsf(v.z), fabsf(v.w))));
  }
  for (int off = 32; off > 0; off >>= 1)
    m = fmaxf(m, __shfl_down(m, off, 64));
  __shared__ float smax[4];
  int l = threadIdx.x & 63, wv = threadIdx.x >> 6;
  if (l == 0) smax[wv] = m;
  __syncthreads();
  if (threadIdx.x == 0) {
    float bm = fmaxf(fmaxf(smax[0], smax[1]), fmaxf(smax[2], smax[3]));
    atomicMax(amax_bits, __float_as_uint(bm));
  }
}

// ---- fused: quantize weight -> bf16 qw, then convert x -> bf16 xb ----
__global__ void prep_kernel(const float* __restrict__ w,
                            const unsigned* __restrict__ amax_bits,
                            ushort_t* __restrict__ qw, int nw4,
                            const float* __restrict__ x,
                            ushort_t* __restrict__ xb, int nx4) {
  float amax = __uint_as_float(*amax_bits);
  float scale = fmaxf(amax / E4M3_MAX, 1e-10f);
  float inv_scale = 1.0f / scale;
  int stride = gridDim.x * blockDim.x;
  int tid0 = blockIdx.x * blockDim.x + threadIdx.x;

  const float4* w4 = (const float4*)w;
  ushort4* q4 = (ushort4*)qw;
  for (int i = tid0; i < nw4; i += stride) {
    float4 v = w4[i];
    float r[4] = {v.x, v.y, v.z, v.w};
    ushort_t o[4];
#pragma unroll
    for (int j = 0; j < 4; ++j) {
      float s = fminf(fmaxf(r[j] * inv_scale, -E4M3_MAX), E4M3_MAX);
      s = __half2float(__float2half(s));   // fp16 round-trip (RNE)
      float q = rintf(s * 8.0f) * 0.125f;  // mantissa grid, half-to-even
      q = fminf(fmaxf(q, -E4M3_MAX), E4M3_MAX);
      __hip_bfloat16 h = __float2bfloat16(q * scale);
      o[j] = *(ushort_t*)&h;
    }
    ushort4 ov = {o[0], o[1], o[2], o[3]};
    q4[i] = ov;
  }

  const float4* x4 = (const float4*)x;
  ushort4* o4 = (ushort4*)xb;
  for (int i = tid0; i < nx4; i += stride) {
    float4 v = x4[i];
    __hip_bfloat16 h0 = __float2bfloat16(v.x);
    __hip_bfloat16 h1 = __float2bfloat16(v.y);
    __hip_bfloat16 h2 = __float2bfloat16(v.z);
    __hip_bfloat16 h3 = __float2bfloat16(v.w);
    ushort4 o = {*(ushort_t*)&h0, *(ushort_t*)&h1,
                 *(ushort_t*)&h2, *(ushort_t*)&h3};
    o4[i] = o;
  }
}

// ============ 256x256 8-phase bf16 GEMM — 32x32x16 MFMA, σ-swizzle (R7) ============
// C = A * Bt^T + bias.  A: [8192][4096] bf16, Bt: [4096][4096] bf16, C fp32.
// 8 waves (2M x 4N), BK=64, dbuf LDS 128 KiB.  R2 phase/stage/vmcnt skeleton:
// reads 12/12/0/0 per K-tile (front-loaded; P3/P4 pure-MFMA), stages
// B(t+1)@P1-2, A(t+2)@P3-4, B(t+2)@P5-6, A(t+3)@P7-8, vmcnt(4)@P4/P8 (never 0
// in steady state).  Swizzle σ(r) = (r&7)^((r>>3)&3): conflict-free under both
// consecutive-16 and mod-4-phased lane grouping (measured 0 conflicts, R7).
// Best measured of 8 structural variants (R2-R14): 267 µs, 47.3% MfmaUtil.

#define BAR() do { asm volatile("" ::: "memory"); \
                   __builtin_amdgcn_s_barrier(); \
                   asm volatile("" ::: "memory"); } while (0)
#define LGKM0() asm volatile("s_waitcnt lgkmcnt(0)" ::: "memory")
#define LGKM8() asm volatile("s_waitcnt lgkmcnt(8)" ::: "memory")
#define VMC4() asm volatile("s_waitcnt vmcnt(4)" ::: "memory")
#define VMC0() asm volatile("s_waitcnt vmcnt(0)" ::: "memory")
#define NOVM() do {} while (0)

__global__ __launch_bounds__(512, 2) void gemm256_w32(
    const ushort_t* __restrict__ A, const ushort_t* __restrict__ Bt,
    const float* __restrict__ bias, float* __restrict__ C) {
  constexpr int K = 4096, N = 4096;
  __shared__ __align__(16) ushort_t As[2][2][8192];
  __shared__ __align__(16) ushort_t Bs[2][2][8192];

  const int tid = threadIdx.x;
  const int wid = tid >> 6, lane = tid & 63;
  const int wm = wid >> 2, wn = wid & 3;     // 2 x 4 wave grid
  const int l31 = lane & 31, lk2 = lane >> 5;

  // XCD swizzle (nwg = 512, divisible by 8)
  int bid = blockIdx.x;
  int swz = (bid & 7) * 64 + (bid >> 3);
  int bm = swz >> 4, bn = swz & 15;          // nbn = 16

  const ushort_t* Ab = A + (size_t)bm * 256 * K;
  const ushort_t* Bb = Bt + (size_t)bn * 256 * K;

  // staging: slot s = q*512+tid; row = s>>3; granule c = (s&7) ^ σ(row),
  // σ(r) = (r&7) ^ ((r>>3)&3)
  int offG[2];
#pragma unroll
  for (int q = 0; q < 2; ++q) {
    int s = q * 512 + tid;
    int row = s >> 3;
    int c = (s & 7) ^ (row & 7) ^ ((row >> 3) & 3);
    offG[q] = row * K + c * 8;
  }

  // stage ONE half-tile (2 loads/thread)
#define STAGE_AH(buf, kt, h)                                               \
  do { _Pragma("unroll") for (int q = 0; q < 2; ++q)                       \
    gload_lds16(Ab + (size_t)(h) * 128 * K + (kt) * 64 + offG[q],          \
                &As[buf][h][(q * 512 + wid * 64) * 8]); } while (0)
#define STAGE_BH(buf, kt, h)                                               \
  do { _Pragma("unroll") for (int q = 0; q < 2; ++q)                       \
    gload_lds16(Bb + (size_t)(h) * 128 * K + (kt) * 64 + offG[q],          \
                &Bs[buf][h][(q * 512 + wid * 64) * 8]); } while (0)

  // swizzled ds_read: granule = (ks*2 + lk2) ^ σ(row); row-group offsets are
  // multiples of 32 so σ(row) = (l31&7) ^ ((l31>>3)&3) is a lane constant.
  const int bhalf = wn >> 1;
  const int brow0 = (wn & 1) * 64;
  const int sig = (l31 & 7) ^ ((l31 >> 3) & 3);
  int xks[4];
#pragma unroll
  for (int ks = 0; ks < 4; ++ks) xks[ks] = ((ks * 2 + lk2) ^ sig) * 8;

  bf16x8 af[4][4], bf[2][4];
  f32x16 acc[4][2] = {};

#define RD_A32(buf, rg)                                                    \
  do { _Pragma("unroll") for (int ks = 0; ks < 4; ++ks)                    \
    af[rg][ks] = *(const bf16x8*)                                          \
        &As[buf][wm][((rg) * 32 + l31) * 64 + xks[ks]]; } while (0)
#define RD_B32(buf)                                                        \
  do { _Pragma("unroll") for (int cg = 0; cg < 2; ++cg)                    \
    _Pragma("unroll") for (int ks = 0; ks < 4; ++ks)                       \
      bf[cg][ks] = *(const bf16x8*)                                        \
          &Bs[buf][bhalf][(brow0 + cg * 32 + l31) * 64 + xks[ks]]; } while (0)

  // 8 MFMA of 32x32x16: one row-group (32 C-rows) x both col-groups x K=64
#define MMA8(rg)                                                           \
  do { __builtin_amdgcn_s_setprio(1);                                      \
    _Pragma("unroll") for (int ks = 0; ks < 4; ++ks) {                     \
      acc[rg][0] = __builtin_amdgcn_mfma_f32_32x32x16_bf16(                \
          af[rg][ks], bf[0][ks], acc[rg][0], 0, 0, 0);                     \
      acc[rg][1] = __builtin_amdgcn_mfma_f32_32x32x16_bf16(                \
          af[rg][ks], bf[1][ks], acc[rg][1], 0, 0, 0);                     \
    }                                                                      \
    __builtin_amdgcn_s_setprio(0); } while (0)

  // One iteration = 2 K-tiles (t in buf0, t+1 in buf1), 8 phases (R2 skeleton).
#define ITER(t, SB1, SA2, SB2, SA3, VM4, VM8)                              \
  do {                                                                     \
    RD_B32(0); RD_A32(0, 0);                                               \
    if (SB1) STAGE_BH(1, (t) + 1, 0);                                      \
    LGKM8(); BAR(); LGKM0(); MMA8(0); BAR();                               \
    RD_A32(0, 1); RD_A32(0, 2); RD_A32(0, 3);                              \
    if (SB1) STAGE_BH(1, (t) + 1, 1);                                      \
    LGKM8(); BAR(); LGKM0(); MMA8(1); BAR();                               \
    if (SA2) STAGE_AH(0, (t) + 2, 0);                                      \
    BAR(); MMA8(2); BAR();                                                 \
    if (SA2) STAGE_AH(0, (t) + 2, 1);                                      \
    BAR(); MMA8(3); VM4; BAR();                                            \
    RD_B32(1); RD_A32(1, 0);                                               \
    if (SB2) STAGE_BH(0, (t) + 2, 0);                                      \
    LGKM8(); BAR(); LGKM0(); MMA8(0); BAR();                               \
    RD_A32(1, 1); RD_A32(1, 2); RD_A32(1, 3);                              \
    if (SB2) STAGE_BH(0, (t) + 2, 1);                                      \
    LGKM8(); BAR(); LGKM0(); MMA8(1); BAR();                               \
    if (SA3) STAGE_AH(1, (t) + 3, 0);                                      \
    BAR(); MMA8(2); BAR();                                                 \
    if (SA3) STAGE_AH(1, (t) + 3, 1);                                      \
    BAR(); MMA8(3); VM8; BAR();                                            \
  } while (0)

  // ---- prologue: tile0 (A,B) + A(1); A(1)'s 4 loads stay in flight ----
  STAGE_AH(0, 0, 0); STAGE_AH(0, 0, 1);
  STAGE_BH(0, 0, 0); STAGE_BH(0, 0, 1);
  STAGE_AH(1, 1, 0); STAGE_AH(1, 1, 1);
  VMC4();
  BAR();

  // ---- main loop: tiles 0..61 ----
  for (int t = 0; t < 62; t += 2)
    ITER(t, 1, 1, 1, 1, VMC4(), VMC4());
  // t=60 stages B(61), A(62), B(62), A(63) — all in range.

  // ---- peeled final iteration: tiles 62,63 (stage B(63) only) ----
  ITER(62, 1, 0, 0, 0, VMC0(), NOVM());

  // ---- C write + bias (32x32 D: col = lane&31, row = (r&3)+8*(r>>2)+4*(lane>>5)) ----
  float* Cb = C + (size_t)(bm * 256 + wm * 128) * N + bn * 256 + wn * 64;
#pragma unroll
  for (int cg = 0; cg < 2; ++cg) {
    int n = cg * 32 + l31;
    float bv = bias[bn * 256 + wn * 64 + n];
#pragma unroll
    for (int rg = 0; rg < 4; ++rg) {
#pragma unroll
      for (int r = 0; r < 16; ++r) {
        int row = rg * 32 + (r & 3) + 8 * (r >> 2) + 4 * lk2;
        Cb[(size_t)row * N + n] = acc[rg][cg][r] + bv;
      }
    }
  }
}

extern "C" void kernel_launch(void* const* d_in, const int* in_sizes, int n_in,
                              void* d_out, int out_size, void* d_ws, size_t ws_size,
                              hipStream_t stream) {
  const float* x = (const float*)d_in[0];     // [4,2048,4096] fp32
  const float* wt = (const float*)d_in[1];    // [4096,4096] fp32
  const float* bias = (const float*)d_in[2];  // [4096] fp32
  float* out = (float*)d_out;                 // [4,2048,4096] fp32

  const int DIN = 4096;
  const int NW = in_sizes[1];                 // 16777216
  const int M = in_sizes[0] / DIN;            // 8192

  char* ws = (char*)d_ws;
  unsigned* amax_bits = (unsigned*)ws;
  ushort_t* qw = (ushort_t*)(ws + 256);                    // bf16 [4096][4096]
  ushort_t* xb = (ushort_t*)(ws + 256 + (size_t)NW * 2);   // bf16 [8192][4096]

  hipMemsetAsync(amax_bits, 0, 4, stream);
  hipLaunchKernelGGL(amax_abs_kernel, dim3(1024), dim3(256), 0, stream,
                     wt, NW / 4, amax_bits);
  hipLaunchKernelGGL(prep_kernel, dim3(2048), dim3(256), 0, stream,
                     wt, amax_bits, qw, NW / 4, x, xb, (M * DIN) / 4);

  hipLaunchKernelGGL(gemm256_w32, dim3(512), dim3(512), 0, stream,
                     xb, qw, bias, out);
}